// Round 1
// baseline (4531.318 us; speedup 1.0000x reference)
//
#include <hip/hip_runtime.h>

#define B_SZ 512
#define T_SZ 256
#define D_SZ 256
#define U_SZ 512

typedef float  f32x4  __attribute__((ext_vector_type(4)));
typedef short  short8 __attribute__((ext_vector_type(8)));
typedef __bf16 bf16x8 __attribute__((ext_vector_type(8)));

static __device__ __forceinline__ unsigned short f2bf(float f) {
  unsigned u = __builtin_bit_cast(unsigned, f);
  return (unsigned short)((u + 0x7FFFu + ((u >> 16) & 1u)) >> 16);
}

static __device__ __forceinline__ f32x4 mfma_bf16(short8 a, short8 b, f32x4 c) {
  return __builtin_amdgcn_mfma_f32_16x16x32_bf16(
      __builtin_bit_cast(bf16x8, a), __builtin_bit_cast(bf16x8, b), c, 0, 0, 0);
}

static __device__ __forceinline__ float sigm(float x) {
  return 1.f / (1.f + __expf(-x));
}
static __device__ __forceinline__ float tanh_fast(float x) {
  // 1 - 2/(e^{2x}+1): safe at +/-inf (no inf/inf)
  return 1.f - 2.f / (__expf(2.f * x) + 1.f);
}

// ---------------- K1: transpose-cast weights into Wt[2048 cols][768 k] bf16 ----
__global__ __launch_bounds__(256) void wt_kernel(const float* __restrict__ Wx,
                                                 const float* __restrict__ Wh,
                                                 unsigned short* __restrict__ Wt) {
  __shared__ float tile[32][33];
  const int ct = blockIdx.x;       // col tile (64)
  const int kt = blockIdx.y;       // k tile (24)
  const int tx = threadIdx.x & 31;
  const int ty = threadIdx.x >> 5; // 0..7
  const int k0 = kt * 32;
#pragma unroll
  for (int q = 0; q < 4; ++q) {
    int kl = ty + q * 8;
    int kg = k0 + kl;
    float v = (kg < 256) ? Wx[(size_t)kg * 2048 + ct * 32 + tx]
                         : Wh[(size_t)(kg - 256) * 2048 + ct * 32 + tx];
    tile[kl][tx] = v;
  }
  __syncthreads();
#pragma unroll
  for (int q = 0; q < 4; ++q) {
    int cl = ty + q * 8;
    Wt[(size_t)(ct * 32 + cl) * 768 + k0 + tx] = f2bf(tile[tx][cl]);
  }
}

// ---------------- K2: persistent fused LSTM ------------------------------------
// grid = 256 WGs (8 batch-groups x 32 u-strips), 256 threads, 96KB dyn LDS.
__global__ __launch_bounds__(256, 1) void lstm_kernel(
    const float* __restrict__ x, const unsigned short* __restrict__ Wt,
    const float* __restrict__ bias, unsigned short* __restrict__ hbuf,
    unsigned* __restrict__ cnt, float* __restrict__ hfin) {
  extern __shared__ char smem[];
  const int tid  = threadIdx.x;
  const int lane = tid & 63;
  const int mw   = tid >> 6;            // wave id 0..3 -> m-tile
  const int g    = blockIdx.x & 7;      // batch group (XCD-swizzle heuristic)
  const int s    = blockIdx.x >> 3;     // u-strip 0..31
  const int col  = lane & 15;
  const int kgrp = lane >> 4;           // 0..3
  const int ug   = s * 16 + col;        // global u column

  // ---- load the wave's full B strip into registers: 24 kt x 4 gates ----
  short8 Bfr[96];
#pragma unroll
  for (int kt = 0; kt < 24; ++kt) {
#pragma unroll
    for (int gg = 0; gg < 4; ++gg) {
      const unsigned short* p =
          Wt + (size_t)(gg * 512 + ug) * 768 + kgrp * 8 + kt * 32;
      Bfr[kt * 4 + gg] = *(const short8*)p;
    }
  }
  float bias_g[4];
#pragma unroll
  for (int gg = 0; gg < 4; ++gg) bias_g[gg] = bias[gg * 512 + ug];

  f32x4 cst = {0.f, 0.f, 0.f, 0.f};
  int p = 0;
  for (int t = 0; t < 256; ++t) {
    // ---- stage A = [x_t | h_{t-1}] into LDS (bf16, XOR-swizzled) ----
#pragma unroll 4
    for (int i = 0; i < 8; ++i) {       // x part: 2048 chunks of 8 f32
      int ch = tid + i * 256;
      int row = ch >> 5;
      int k0 = (ch & 31) * 8;
      const float* xp = x + ((size_t)(g * 64 + row) * T_SZ + t) * D_SZ + k0;
      float4 a  = *(const float4*)xp;
      float4 b2 = *(const float4*)(xp + 4);
      short8 v;
      v[0] = (short)f2bf(a.x);  v[1] = (short)f2bf(a.y);
      v[2] = (short)f2bf(a.z);  v[3] = (short)f2bf(a.w);
      v[4] = (short)f2bf(b2.x); v[5] = (short)f2bf(b2.y);
      v[6] = (short)f2bf(b2.z); v[7] = (short)f2bf(b2.w);
      unsigned byte = ((unsigned)(row * 1536 + k0 * 2)) ^ ((row & 7) << 4);
      *(short8*)(smem + byte) = v;
    }
    const unsigned short* hr = hbuf + ((size_t)p << 18) + ((size_t)(g * 64) << 9);
#pragma unroll 8
    for (int i = 0; i < 16; ++i) {      // h part: 4096 chunks of 8 bf16
      int ch = tid + i * 256;
      int row = ch >> 6;
      int k0 = (ch & 63) * 8;
      short8 v = *(const short8*)(hr + ((size_t)row << 9) + k0);
      unsigned byte =
          ((unsigned)(row * 1536 + (256 + k0) * 2)) ^ ((row & 7) << 4);
      *(short8*)(smem + byte) = v;
    }
    __syncthreads();

    // ---- GEMM: z[16 rows x 64 z-cols] per wave, weights from VGPRs ----
    f32x4 acc[4];
#pragma unroll
    for (int gg = 0; gg < 4; ++gg) acc[gg] = (f32x4){0.f, 0.f, 0.f, 0.f};
    const int arow = mw * 16 + col;
    const unsigned abase = (unsigned)(arow * 1536) ^ ((arow & 7) << 4);
#pragma unroll
    for (int kt = 0; kt < 24; ++kt) {
      unsigned byte = ((unsigned)(arow * 1536 + (kgrp * 8 + kt * 32) * 2)) ^
                      ((arow & 7) << 4);
      short8 af = *(const short8*)(smem + byte);
      acc[0] = mfma_bf16(af, Bfr[kt * 4 + 0], acc[0]);
      acc[1] = mfma_bf16(af, Bfr[kt * 4 + 1], acc[1]);
      acc[2] = mfma_bf16(af, Bfr[kt * 4 + 2], acc[2]);
      acc[3] = mfma_bf16(af, Bfr[kt * 4 + 3], acc[3]);
    }
    (void)abase;

    // ---- gates + state update (lane-local: all 4 gates share (row,u)) ----
#pragma unroll
    for (int j = 0; j < 4; ++j) {
      float zi = acc[0][j] + bias_g[0];
      float zf = acc[1][j] + bias_g[1];
      float zg = acc[2][j] + bias_g[2];
      float zo = acc[3][j] + bias_g[3];
      float ii = sigm(zi);
      float ff = sigm(zf);
      float gv = tanh_fast(zg);
      float oo = sigm(zo);
      float cv = ff * cst[j] + ii * gv;
      cst[j] = cv;
      float hv = oo * tanh_fast(cv);
      int brow = g * 64 + mw * 16 + kgrp * 4 + j;
      if (t == 255) {
        hfin[(size_t)brow * 512 + ug] = hv;
      } else {
        hbuf[((size_t)(p ^ 1) << 18) + ((size_t)brow << 9) + ug] = f2bf(hv);
      }
    }

    if (t == 255) break;

    // ---- group barrier: 32 WGs of this batch-group ----
    __syncthreads();  // drains vmem (h stores) per-wave before release
    if (tid == 0) {
      unsigned* cp = cnt + (g << 8) + t;
      __hip_atomic_fetch_add(cp, 1u, __ATOMIC_ACQ_REL, __HIP_MEMORY_SCOPE_AGENT);
      while (__hip_atomic_load(cp, __ATOMIC_RELAXED, __HIP_MEMORY_SCOPE_AGENT) <
             32u)
        __builtin_amdgcn_s_sleep(1);
      (void)__hip_atomic_load(cp, __ATOMIC_ACQUIRE, __HIP_MEMORY_SCOPE_AGENT);
    }
    __syncthreads();
    p ^= 1;
  }
}

// ---------------- K3: MLP head + softmax ---------------------------------------
__global__ __launch_bounds__(128) void mlp_kernel(
    const float* __restrict__ hfin, const float* __restrict__ W1,
    const float* __restrict__ b1, const float* __restrict__ W2,
    const float* __restrict__ b2, float* __restrict__ out) {
  __shared__ float hrow[512];
  __shared__ float act[128];
  __shared__ float lg[10];
  const int b = blockIdx.x;
  const int tid = threadIdx.x;
#pragma unroll
  for (int i = 0; i < 4; ++i)
    hrow[tid + i * 128] = hfin[(size_t)b * 512 + tid + i * 128];
  __syncthreads();
  float s = b1[tid];
#pragma unroll 8
  for (int k = 0; k < 512; ++k) s += hrow[k] * W1[(size_t)k * 128 + tid];
  act[tid] = fmaxf(s, 0.f);
  __syncthreads();
  if (tid < 10) {
    float l = b2[tid];
#pragma unroll 8
    for (int k = 0; k < 128; ++k) l += act[k] * W2[(size_t)k * 10 + tid];
    lg[tid] = l;
  }
  __syncthreads();
  if (tid == 0) {
    float m = lg[0];
    for (int j = 1; j < 10; ++j) m = fmaxf(m, lg[j]);
    float e[10];
    float sum = 0.f;
    for (int j = 0; j < 10; ++j) {
      e[j] = expf(lg[j] - m);
      sum += e[j];
    }
    float inv = 1.f / sum;
    for (int j = 0; j < 10; ++j) out[(size_t)b * 10 + j] = e[j] * inv;
  }
}

extern "C" void kernel_launch(void* const* d_in, const int* in_sizes, int n_in,
                              void* d_out, int out_size, void* d_ws,
                              size_t ws_size, hipStream_t stream) {
  const float* x    = (const float*)d_in[0];
  const float* Wx   = (const float*)d_in[1];
  const float* Wh   = (const float*)d_in[2];
  const float* bias = (const float*)d_in[3];
  const float* W1   = (const float*)d_in[4];
  const float* b1   = (const float*)d_in[5];
  const float* W2   = (const float*)d_in[6];
  const float* b2   = (const float*)d_in[7];
  float* out = (float*)d_out;

  char* ws = (char*)d_ws;
  // layout: [0,1MB) hbuf[2][512][512] bf16 | [1MB,+8KB) counters |
  //         [2MB,+3MB) Wt bf16 | [5MB,+1MB) h_final f32
  unsigned short* hbuf = (unsigned short*)ws;
  unsigned* cnt        = (unsigned*)(ws + 1048576);
  unsigned short* Wt   = (unsigned short*)(ws + 2097152);
  float* hfin          = (float*)(ws + 2097152 + 3145728);

  // zero h0 (both parities) + barrier counters; ws is re-poisoned every call
  hipMemsetAsync(d_ws, 0, 1048576 + 8192, stream);

  wt_kernel<<<dim3(64, 24), 256, 0, stream>>>(Wx, Wh, Wt);

  hipFuncSetAttribute((const void*)lstm_kernel,
                      hipFuncAttributeMaxDynamicSharedMemorySize, 98304);
  lstm_kernel<<<256, 256, 98304, stream>>>(x, Wt, bias, hbuf, cnt, hfin);

  mlp_kernel<<<512, 128, 0, stream>>>(hfin, W1, b1, W2, b2, out);
}

// Round 5
// 2643.983 us; speedup vs baseline: 1.7138x; 1.7138x over previous
//
#include <hip/hip_runtime.h>

#define B_SZ 512
#define T_SZ 256
#define D_SZ 256
#define U_SZ 512

typedef float  f32x4  __attribute__((ext_vector_type(4)));
typedef short  short8 __attribute__((ext_vector_type(8)));
typedef __bf16 bf16x8 __attribute__((ext_vector_type(8)));

static __device__ __forceinline__ unsigned short f2bf(float f) {
  unsigned u = __builtin_bit_cast(unsigned, f);
  return (unsigned short)((u + 0x7FFFu + ((u >> 16) & 1u)) >> 16);
}

static __device__ __forceinline__ f32x4 mfma_bf16(short8 a, short8 b, f32x4 c) {
  return __builtin_amdgcn_mfma_f32_16x16x32_bf16(
      __builtin_bit_cast(bf16x8, a), __builtin_bit_cast(bf16x8, b), c, 0, 0, 0);
}

static __device__ __forceinline__ float sigm(float x) {
  return 1.f / (1.f + __expf(-x));
}
static __device__ __forceinline__ float tanh_fast(float x) {
  return 1.f - 2.f / (__expf(2.f * x) + 1.f);  // safe at +/-inf
}

// ---------------- K1: transpose-cast weights into Wt[2048 cols][768 k] bf16 ----
__global__ __launch_bounds__(256) void wt_kernel(const float* __restrict__ Wx,
                                                 const float* __restrict__ Wh,
                                                 unsigned short* __restrict__ Wt) {
  __shared__ float tile[32][33];
  const int ct = blockIdx.x;       // col tile (64)
  const int kt = blockIdx.y;       // k tile (24)
  const int tx = threadIdx.x & 31;
  const int ty = threadIdx.x >> 5; // 0..7
  const int k0 = kt * 32;
#pragma unroll
  for (int q = 0; q < 4; ++q) {
    int kl = ty + q * 8;
    int kg = k0 + kl;
    float v = (kg < 256) ? Wx[(size_t)kg * 2048 + ct * 32 + tx]
                         : Wh[(size_t)(kg - 256) * 2048 + ct * 32 + tx];
    tile[kl][tx] = v;
  }
  __syncthreads();
#pragma unroll
  for (int q = 0; q < 4; ++q) {
    int cl = ty + q * 8;
    Wt[(size_t)(ct * 32 + cl) * 768 + k0 + tx] = f2bf(tile[tx][cl]);
  }
}

// ---------------- K2: persistent fused LSTM ------------------------------------
// grid = 256 WGs: 16 batch-groups (32 rows) x 16 u-strips (32 u = 128 z-cols).
// 256 threads = 4 waves = 2 m-tiles x 2 u-halves. Weights in registers.
// Cross-WG h exchange: relaxed agent-scope atomics (L3 coherence point), NO
// fences -> no per-step L2 invalidation. Parity double-buffer + per-(g,t)
// counters; __syncthreads() drains vmcnt before the counter increment.
__global__ __launch_bounds__(256, 1) void lstm_kernel(
    const float* __restrict__ x, const unsigned short* __restrict__ Wt,
    const float* __restrict__ bias, unsigned short* __restrict__ hbuf,
    unsigned* __restrict__ cnt, float* __restrict__ hfin) {
  extern __shared__ char smem[];
  const int tid  = threadIdx.x;
  const int lane = tid & 63;
  const int wv   = tid >> 6;            // 0..3
  const int mt   = wv & 1;              // m-tile (16 rows)
  const int uh   = wv >> 1;             // u-half within strip
  const int g    = blockIdx.x & 15;     // batch group (g&7 ~ XCD co-location)
  const int s    = blockIdx.x >> 4;     // u-strip 0..15
  const int col  = lane & 15;
  const int kgrp = lane >> 4;           // 0..3
  const int ug   = s * 32 + uh * 16 + col;  // global u column

  // ---- load the wave's B strip into registers: 24 kt x 4 gates ----
  short8 Bfr[96];
#pragma unroll
  for (int kt = 0; kt < 24; ++kt) {
#pragma unroll
    for (int gg = 0; gg < 4; ++gg) {
      const unsigned short* p =
          Wt + (size_t)(gg * 512 + ug) * 768 + kgrp * 8 + kt * 32;
      Bfr[kt * 4 + gg] = *(const short8*)p;
    }
  }
  float bias_g[4];
#pragma unroll
  for (int gg = 0; gg < 4; ++gg) bias_g[gg] = bias[gg * 512 + ug];

  f32x4 cst = {0.f, 0.f, 0.f, 0.f};
  int p = 0;
  for (int t = 0; t < 256; ++t) {
    // ---- wait for step t-1 of this group (tid0 relaxed spin, no fence) ----
    if (t > 0) {
      if (tid == 0) {
        const unsigned* cp = cnt + (g << 8) + (t - 1);
        while (__hip_atomic_load(cp, __ATOMIC_RELAXED,
                                 __HIP_MEMORY_SCOPE_AGENT) < 16u) {
        }
      }
      __syncthreads();
    }

    // ---- stage x_t (normal cached loads, f32 -> bf16) ----
#pragma unroll
    for (int i = 0; i < 4; ++i) {       // 1024 chunks of 8 f32
      int ch = tid + i * 256;
      int row = ch >> 5;
      int k0 = (ch & 31) * 8;
      const float* xp = x + ((size_t)(g * 32 + row) * T_SZ + t) * D_SZ + k0;
      float4 a  = *(const float4*)xp;
      float4 b2 = *(const float4*)(xp + 4);
      short8 v;
      v[0] = (short)f2bf(a.x);  v[1] = (short)f2bf(a.y);
      v[2] = (short)f2bf(a.z);  v[3] = (short)f2bf(a.w);
      v[4] = (short)f2bf(b2.x); v[5] = (short)f2bf(b2.y);
      v[6] = (short)f2bf(b2.z); v[7] = (short)f2bf(b2.w);
      unsigned byte = ((unsigned)(row * 1536 + k0 * 2)) ^ ((row & 7) << 4);
      *(short8*)(smem + byte) = v;
    }
    // ---- stage h_{t-1} (relaxed agent-scope u64 loads: L3, never stale) ----
    const unsigned short* hr =
        hbuf + ((size_t)p << 18) + ((size_t)(g * 32) << 9);
#pragma unroll
    for (int i = 0; i < 16; ++i) {      // 4096 u64 chunks (4 bf16 each)
      int ch = tid + i * 256;
      int row = ch >> 7;
      int c4 = ch & 127;
      const unsigned long long* hp =
          (const unsigned long long*)(hr + ((size_t)row << 9) + c4 * 4);
      unsigned long long v = __hip_atomic_load(hp, __ATOMIC_RELAXED,
                                               __HIP_MEMORY_SCOPE_AGENT);
      unsigned byte =
          ((unsigned)(row * 1536 + (256 + c4 * 4) * 2)) ^ ((row & 7) << 4);
      *(unsigned long long*)(smem + byte) = v;
    }
    __syncthreads();

    // ---- GEMM: z[16 rows x 64 z-cols] per wave, weights from VGPR/AGPR ----
    f32x4 acc[4];
#pragma unroll
    for (int gg = 0; gg < 4; ++gg) acc[gg] = (f32x4){0.f, 0.f, 0.f, 0.f};
    const int arow = mt * 16 + col;
#pragma unroll
    for (int kt = 0; kt < 24; ++kt) {
      unsigned byte = ((unsigned)(arow * 1536 + (kgrp * 8 + kt * 32) * 2)) ^
                      ((arow & 7) << 4);
      short8 af = *(const short8*)(smem + byte);
      acc[0] = mfma_bf16(af, Bfr[kt * 4 + 0], acc[0]);
      acc[1] = mfma_bf16(af, Bfr[kt * 4 + 1], acc[1]);
      acc[2] = mfma_bf16(af, Bfr[kt * 4 + 2], acc[2]);
      acc[3] = mfma_bf16(af, Bfr[kt * 4 + 3], acc[3]);
    }

    // ---- gates + state update (lane-local) ----
#pragma unroll
    for (int j = 0; j < 4; ++j) {
      float zi = acc[0][j] + bias_g[0];
      float zf = acc[1][j] + bias_g[1];
      float zg = acc[2][j] + bias_g[2];
      float zo = acc[3][j] + bias_g[3];
      float ii = sigm(zi);
      float ff = sigm(zf);
      float gv = tanh_fast(zg);
      float oo = sigm(zo);
      float cv = ff * cst[j] + ii * gv;
      cst[j] = cv;
      float hv = oo * tanh_fast(cv);
      int brow = g * 32 + mt * 16 + kgrp * 4 + j;
      if (t == 255) {
        hfin[(size_t)brow * 512 + ug] = hv;
      } else {
        unsigned short* hp =
            hbuf + (((size_t)(p ^ 1)) << 18) + ((size_t)brow << 9) + ug;
        __hip_atomic_store(hp, f2bf(hv), __ATOMIC_RELAXED,
                           __HIP_MEMORY_SCOPE_AGENT);
      }
    }

    if (t == 255) break;

    // ---- arrive: vmcnt drained by syncthreads, then relaxed increment ----
    __syncthreads();
    if (tid == 0) {
      __hip_atomic_fetch_add(cnt + (g << 8) + t, 1u, __ATOMIC_RELAXED,
                             __HIP_MEMORY_SCOPE_AGENT);
    }
    p ^= 1;
  }
}

// ---------------- K3: MLP head + softmax ---------------------------------------
__global__ __launch_bounds__(128) void mlp_kernel(
    const float* __restrict__ hfin, const float* __restrict__ W1,
    const float* __restrict__ b1, const float* __restrict__ W2,
    const float* __restrict__ b2, float* __restrict__ out) {
  __shared__ float hrow[512];
  __shared__ float act[128];
  __shared__ float lg[10];
  const int b = blockIdx.x;
  const int tid = threadIdx.x;
#pragma unroll
  for (int i = 0; i < 4; ++i)
    hrow[tid + i * 128] = hfin[(size_t)b * 512 + tid + i * 128];
  __syncthreads();
  float s = b1[tid];
#pragma unroll 8
  for (int k = 0; k < 512; ++k) s += hrow[k] * W1[(size_t)k * 128 + tid];
  act[tid] = fmaxf(s, 0.f);
  __syncthreads();
  if (tid < 10) {
    float l = b2[tid];
#pragma unroll 8
    for (int k = 0; k < 128; ++k) l += act[k] * W2[(size_t)k * 10 + tid];
    lg[tid] = l;
  }
  __syncthreads();
  if (tid == 0) {
    float m = lg[0];
    for (int j = 1; j < 10; ++j) m = fmaxf(m, lg[j]);
    float e[10];
    float sum = 0.f;
    for (int j = 0; j < 10; ++j) {
      e[j] = expf(lg[j] - m);
      sum += e[j];
    }
    float inv = 1.f / sum;
    for (int j = 0; j < 10; ++j) out[(size_t)b * 10 + j] = e[j] * inv;
  }
}

extern "C" void kernel_launch(void* const* d_in, const int* in_sizes, int n_in,
                              void* d_out, int out_size, void* d_ws,
                              size_t ws_size, hipStream_t stream) {
  const float* x    = (const float*)d_in[0];
  const float* Wx   = (const float*)d_in[1];
  const float* Wh   = (const float*)d_in[2];
  const float* bias = (const float*)d_in[3];
  const float* W1   = (const float*)d_in[4];
  const float* b1   = (const float*)d_in[5];
  const float* W2   = (const float*)d_in[6];
  const float* b2   = (const float*)d_in[7];
  float* out = (float*)d_out;

  char* ws = (char*)d_ws;
  // layout: [0,1MB) hbuf[2][512][512] bf16 | [1MB,+16KB) counters |
  //         [2MB,+3MB) Wt bf16 | [5MB,+1MB) h_final f32
  unsigned short* hbuf = (unsigned short*)ws;
  unsigned* cnt        = (unsigned*)(ws + 1048576);
  unsigned short* Wt   = (unsigned short*)(ws + 2097152);
  float* hfin          = (float*)(ws + 2097152 + 3145728);

  // zero h0 (both parities) + barrier counters; ws is re-poisoned every call
  hipMemsetAsync(d_ws, 0, 1048576 + 16384, stream);

  wt_kernel<<<dim3(64, 24), 256, 0, stream>>>(Wx, Wh, Wt);

  hipFuncSetAttribute((const void*)lstm_kernel,
                      hipFuncAttributeMaxDynamicSharedMemorySize, 49152);
  lstm_kernel<<<256, 256, 49152, stream>>>(x, Wt, bias, hbuf, cnt, hfin);

  mlp_kernel<<<512, 128, 0, stream>>>(hfin, W1, b1, W2, b2, out);
}